// Round 1
// baseline (277.206 us; speedup 1.0000x reference)
//
#include <hip/hip_runtime.h>

// Problem constants (reference: N=16, A=2048, B=2048, H=64)
#define NB 16
#define AQ 2048
#define BKV 2048
#define HD 64

typedef float f32x4 __attribute__((ext_vector_type(4)));
typedef short bf16x8 __attribute__((ext_vector_type(8)));
typedef short short4v __attribute__((ext_vector_type(4)));
typedef int int4v __attribute__((ext_vector_type(4)));

__device__ __forceinline__ short f2bf(float f) {
  return __builtin_bit_cast(short, static_cast<__bf16>(f));
}

// Flash attention, swapped-QK^T formulation.
// Block = 256 threads = 4 waves; each wave owns 16 q rows; QBLK per block = 64.
// Grid = N * (A/64) = 512 blocks, XCD-bijective swizzle (2 batches per XCD L2).
__global__ __launch_bounds__(256, 2) void attn_fwd(
    const float* __restrict__ Q, const float* __restrict__ K,
    const float* __restrict__ V, const int* __restrict__ M,
    float* __restrict__ O) {
  // bijective XCD swizzle: nwg=512, 64 contiguous wgs per XCD
  unsigned orig = blockIdx.x;
  unsigned wg = (orig & 7u) * 64u + (orig >> 3);
  int n = (int)(wg >> 5);        // 32 q-tiles per batch
  int qtile = (int)(wg & 31u);

  int w = threadIdx.x >> 6;      // wave 0..3
  int lane = threadIdx.x & 63;
  int g = lane >> 4;             // 4-lane-group id 0..3
  int c = lane & 15;             // col-in-fragment

  int qw = qtile * 64 + w * 16;  // this wave's q base

  const float* Qn = Q + (size_t)n * AQ * HD;
  const float* Kn = K + (size_t)n * BKV * HD;
  const float* Vn = V + (size_t)n * BKV * HD;
  const int* Mn = M + (size_t)n * BKV;

  // per-wave private P staging: [16 q rows][72 bf16] (pad 64->72 kills bank conflicts)
  __shared__ __align__(16) short Plds[4][16][72];

  // ---- Q fragments (B operand of swapped QK^T), scale 1/sqrt(64)=0.125 folded in
  // B[k=h][j=q]: lane holds q = qw + c, h = 32*ks + 8*g + i  (8 contiguous f32)
  bf16x8 qb[2];
#pragma unroll
  for (int ks = 0; ks < 2; ++ks) {
    const float* qp = Qn + (size_t)(qw + c) * HD + 32 * ks + 8 * g;
    f32x4 q0 = *(const f32x4*)qp;
    f32x4 q1 = *(const f32x4*)(qp + 4);
#pragma unroll
    for (int i = 0; i < 4; ++i) {
      qb[ks][i]     = f2bf(q0[i] * 0.125f);
      qb[ks][i + 4] = f2bf(q1[i] * 0.125f);
    }
  }

  // C accumulator: acc[th][r] = C[q = 4*g + r][h = 16*th + c]
  f32x4 acc[4] = {};
  float m_run = -1e30f;
  float l_run = 0.f;

  for (int b0 = 0; b0 < BKV; b0 += 64) {
    // ---- S^T = K . Q^T : st[t][r] = S^T[b = 16t + 4g + r][q = c]
    f32x4 st[4];
#pragma unroll
    for (int t = 0; t < 4; ++t) {
      f32x4 z = {0.f, 0.f, 0.f, 0.f};
#pragma unroll
      for (int ks = 0; ks < 2; ++ks) {
        // A[i=b][k=h]: lane holds b = b0+16t+c, h = 32*ks+8*g+i (8 contiguous f32)
        const float* kp = Kn + (size_t)(b0 + 16 * t + c) * HD + 32 * ks + 8 * g;
        f32x4 k0 = *(const f32x4*)kp;
        f32x4 k1 = *(const f32x4*)(kp + 4);
        bf16x8 ka;
#pragma unroll
        for (int i = 0; i < 4; ++i) {
          ka[i]     = f2bf(k0[i]);
          ka[i + 4] = f2bf(k1[i]);
        }
        z = __builtin_amdgcn_mfma_f32_16x16x32_bf16(ka, qb[ks], z, 0, 0, 0);
      }
      st[t] = z;
    }

    // ---- mask + row max (row = fixed q = c; spread over t, r, and lane groups)
    float p[4][4];
    float mt = -1e30f;
#pragma unroll
    for (int t = 0; t < 4; ++t) {
      int4v mv = *(const int4v*)(Mn + b0 + 16 * t + 4 * g);
#pragma unroll
      for (int r = 0; r < 4; ++r) {
        float s = mv[r] ? -1e30f : st[t][r];
        p[t][r] = s;
        mt = fmaxf(mt, s);
      }
    }
    mt = fmaxf(mt, __shfl_xor(mt, 16));
    mt = fmaxf(mt, __shfl_xor(mt, 32));
    float m_new = fmaxf(m_run, mt);
    float fac = exp2f((m_run - m_new) * 1.44269504f);

    // ---- P = exp(S - m), masked entries exactly 0 (robust to all-masked tiles)
    float rs = 0.f;
#pragma unroll
    for (int t = 0; t < 4; ++t) {
#pragma unroll
      for (int r = 0; r < 4; ++r) {
        float s = p[t][r];
        float e = (s <= -1e29f) ? 0.f : exp2f((s - m_new) * 1.44269504f);
        p[t][r] = e;
        rs += e;
      }
    }
    rs += __shfl_xor(rs, 16);
    rs += __shfl_xor(rs, 32);
    l_run = l_run * fac + rs;
    m_run = m_new;

    // ---- rescale accumulator: acc row q = 4g + r needs factor from lane (4g+r)
#pragma unroll
    for (int r = 0; r < 4; ++r) {
      float fr = __shfl(fac, 4 * g + r);
#pragma unroll
      for (int th = 0; th < 4; ++th) acc[th][r] *= fr;
    }

    // ---- P -> LDS (layout P[q][b], per-wave private; no block barrier needed)
#pragma unroll
    for (int t = 0; t < 4; ++t) {
      short4v pk;
#pragma unroll
      for (int r = 0; r < 4; ++r) pk[r] = f2bf(p[t][r]);
      *(short4v*)(&Plds[w][c][16 * t + 4 * g]) = pk;  // b = 16t + 4g .. +3
    }

    // ---- PV: A = P[q=c][b = 32ks + 8g + i], B = V[b][h = 16th + c]
    bf16x8 pa[2];
#pragma unroll
    for (int ks = 0; ks < 2; ++ks)
      pa[ks] = *(const bf16x8*)(&Plds[w][c][32 * ks + 8 * g]);
#pragma unroll
    for (int th = 0; th < 4; ++th) {
#pragma unroll
      for (int ks = 0; ks < 2; ++ks) {
        const float* vp = Vn + (size_t)(b0 + 32 * ks + 8 * g) * HD + 16 * th + c;
        bf16x8 vb;
#pragma unroll
        for (int i = 0; i < 8; ++i) vb[i] = f2bf(vp[(size_t)i * HD]);
        acc[th] = __builtin_amdgcn_mfma_f32_16x16x32_bf16(pa[ks], vb, acc[th], 0, 0, 0);
      }
    }
  }

  // ---- epilogue: normalize by l (per accumulator row), write f32 output
#pragma unroll
  for (int r = 0; r < 4; ++r) {
    float lr = __shfl(l_run, 4 * g + r);
    float inv = 1.0f / lr;
    int qrow = qw + 4 * g + r;
    float* op = O + ((size_t)n * AQ + qrow) * HD + c;
#pragma unroll
    for (int th = 0; th < 4; ++th) op[16 * th] = acc[th][r] * inv;
  }
}

extern "C" void kernel_launch(void* const* d_in, const int* in_sizes, int n_in,
                              void* d_out, int out_size, void* d_ws, size_t ws_size,
                              hipStream_t stream) {
  const float* q = (const float*)d_in[0];
  const float* k = (const float*)d_in[1];
  const float* v = (const float*)d_in[2];
  const int* m = (const int*)d_in[3];
  float* o = (float*)d_out;
  attn_fwd<<<dim3(NB * (AQ / 64)), dim3(256), 0, stream>>>(q, k, v, m, o);
}